// Round 1
// baseline (2770.323 us; speedup 1.0000x reference)
//
#include <hip/hip_runtime.h>

#define NN   1601
#define EMB  300
#define EMBV 75    // EMB/4 float4 groups
#define NB   2048
#define L    64

// ---------------------------------------------------------------------------
// t0[n][e] = sum_k emb[n][k] * w0[e][k]      (1601 x 300 output, tiny GEMM)
// ---------------------------------------------------------------------------
__global__ __launch_bounds__(320) void k_t0(const float* __restrict__ emb,
                                            const float* __restrict__ w0,
                                            float* __restrict__ t0) {
  __shared__ float4 row4[EMBV];
  int n = blockIdx.x;
  for (int k = threadIdx.x; k < EMB; k += 320)
    ((float*)row4)[k] = emb[(size_t)n * EMB + k];
  __syncthreads();
  int e = threadIdx.x;
  if (e < EMB) {
    const float4* w4 = (const float4*)w0 + (size_t)e * EMBV;
    float ax = 0.f, ay = 0.f, az = 0.f, aw = 0.f;
    for (int k4 = 0; k4 < EMBV; ++k4) {
      float4 hv = row4[k4];
      float4 wv = w4[k4];
      ax += hv.x * wv.x; ay += hv.y * wv.y;
      az += hv.z * wv.z; aw += hv.w * wv.w;
    }
    t0[(size_t)n * EMB + e] = (ax + ay) + (az + aw);
  }
}

// ---------------------------------------------------------------------------
// adj[b] = norm(in_adj[lab x lab] + I);  d[j] = (sum_i m[i][j])^-0.5
// adj[b][i][j] = m[i][j] * d[i] * d[j]
// ---------------------------------------------------------------------------
__global__ __launch_bounds__(256) void k_adj(const int* __restrict__ labels,
                                             const float* __restrict__ in_adj,
                                             float* __restrict__ adj_out) {
  __shared__ int   lab[L];
  __shared__ float nb[L][L + 1];
  __shared__ float ps[4][L];
  __shared__ float dv[L];
  int b   = blockIdx.x;
  int tid = threadIdx.x;
  if (tid < L) lab[tid] = labels[(size_t)b * L + tid];
  __syncthreads();
  for (int idx = tid; idx < L * L; idx += 256) {
    int i = idx >> 6, j = idx & 63;
    float v = in_adj[(size_t)lab[i] * NN + lab[j]];
    if (i == j) v += 1.f;
    nb[i][j] = v;
  }
  __syncthreads();
  {
    int j = tid & 63, q = tid >> 6;
    float s = 0.f;
    #pragma unroll
    for (int i = 0; i < 16; ++i) s += nb[q * 16 + i][j];
    ps[q][j] = s;
  }
  __syncthreads();
  if (tid < L) {
    float s = ps[0][tid] + ps[1][tid] + ps[2][tid] + ps[3][tid];
    dv[tid] = 1.0f / sqrtf(s);
  }
  __syncthreads();
  for (int idx = tid; idx < L * L; idx += 256) {
    int i = idx >> 6, j = idx & 63;
    adj_out[(size_t)b * (L * L) + idx] = nb[i][j] * dv[i] * dv[j];
  }
}

// ---------------------------------------------------------------------------
// layer 0: hout[b][i][e] = sum_j adj[b][i][j] * t0[lab[b][j]][e]
// ---------------------------------------------------------------------------
__global__ __launch_bounds__(256) void k_layer0(const int* __restrict__ labels,
                                                const float* __restrict__ t0,
                                                const float* __restrict__ adj,
                                                float* __restrict__ hout) {
  __shared__ int    lab[L];
  __shared__ float  am[L][L + 1];
  __shared__ float4 hj4[L][77];   // gathered t0 rows, padded stride 308 floats
  int b   = blockIdx.x;
  int tid = threadIdx.x;
  if (tid < L) lab[tid] = labels[(size_t)b * L + tid];
  for (int idx = tid; idx < L * L; idx += 256)
    am[idx >> 6][idx & 63] = adj[(size_t)b * (L * L) + idx];
  __syncthreads();
  for (int idx = tid; idx < L * EMB; idx += 256) {
    int j = idx / EMB;
    int k = idx - j * EMB;
    ((float*)&hj4[j][0])[k] = t0[(size_t)lab[j] * EMB + k];
  }
  __syncthreads();
  int i = tid & 63, cg = tid >> 6;
  float* ob = hout + ((size_t)b * L + i) * EMB;
  for (int cb = 0; cb < EMB; cb += 16) {
    int width = EMB - cb; if (width > 16) width = 16;
    if (4 * cg < width) {
      int g = (cb >> 2) + cg;
      float ox = 0.f, oy = 0.f, oz = 0.f, ow = 0.f;
      #pragma unroll 8
      for (int j = 0; j < L; ++j) {
        float  a  = am[i][j];
        float4 tv = hj4[j][g];
        ox += a * tv.x; oy += a * tv.y; oz += a * tv.z; ow += a * tv.w;
      }
      *(float4*)&ob[cb + 4 * cg] = make_float4(ox, oy, oz, ow);
    }
  }
}

// ---------------------------------------------------------------------------
// fused layer (in-place): h[b] = adj[b] @ (h[b] @ W^T)
// per 16-col chunk: stage W rows -> LDS, t = h@W^T chunk, hout = adj@t chunk
// ---------------------------------------------------------------------------
__global__ __launch_bounds__(256) void k_layerF(const float* __restrict__ Wl,
                                                const float* __restrict__ adj,
                                                float* __restrict__ h) {
  __shared__ float4 h4[L][77];       // h[b] staged, padded stride 308 floats
  __shared__ float  am[L][L + 1];
  __shared__ float  tb[L][16];
  __shared__ float  wcs[16 * EMB];   // W chunk rows, stride 300 (16B-aligned rows)
  int b   = blockIdx.x;
  int tid = threadIdx.x;
  float* hb = h + (size_t)b * (L * EMB);
  for (int idx = tid; idx < L * EMB; idx += 256) {
    int r = idx / EMB;
    int k = idx - r * EMB;
    ((float*)&h4[r][0])[k] = hb[idx];
  }
  for (int idx = tid; idx < L * L; idx += 256)
    am[idx >> 6][idx & 63] = adj[(size_t)b * (L * L) + idx];
  __syncthreads();

  int r = tid & 63, cg = tid >> 6;
  for (int cb = 0; cb < EMB; cb += 16) {
    int width = EMB - cb; if (width > 16) width = 16;
    // stage W rows cb..cb+width-1 (contiguous) into LDS
    const float* wsrc = Wl + (size_t)cb * EMB;
    for (int idx = tid; idx < width * EMB; idx += 256) wcs[idx] = wsrc[idx];
    __syncthreads();

    bool act = (4 * cg) < width;
    if (act) {
      const float4* w0p = (const float4*)&wcs[(4 * cg + 0) * EMB];
      const float4* w1p = (const float4*)&wcs[(4 * cg + 1) * EMB];
      const float4* w2p = (const float4*)&wcs[(4 * cg + 2) * EMB];
      const float4* w3p = (const float4*)&wcs[(4 * cg + 3) * EMB];
      float a0 = 0.f, a1 = 0.f, a2 = 0.f, a3 = 0.f;
      for (int k4 = 0; k4 < EMBV; ++k4) {
        float4 hv = h4[r][k4];
        float4 w0 = w0p[k4];
        float4 w1 = w1p[k4];
        float4 w2 = w2p[k4];
        float4 w3 = w3p[k4];
        a0 += hv.x * w0.x + hv.y * w0.y + hv.z * w0.z + hv.w * w0.w;
        a1 += hv.x * w1.x + hv.y * w1.y + hv.z * w1.z + hv.w * w1.w;
        a2 += hv.x * w2.x + hv.y * w2.y + hv.z * w2.z + hv.w * w2.w;
        a3 += hv.x * w3.x + hv.y * w3.y + hv.z * w3.z + hv.w * w3.w;
      }
      tb[r][4 * cg + 0] = a0;
      tb[r][4 * cg + 1] = a1;
      tb[r][4 * cg + 2] = a2;
      tb[r][4 * cg + 3] = a3;
    }
    __syncthreads();
    if (act) {
      float ox = 0.f, oy = 0.f, oz = 0.f, ow = 0.f;
      #pragma unroll 8
      for (int j = 0; j < L; ++j) {
        float  a  = am[r][j];
        float4 tv = *(const float4*)&tb[j][4 * cg];
        ox += a * tv.x; oy += a * tv.y; oz += a * tv.z; ow += a * tv.w;
      }
      *(float4*)&hb[(size_t)r * EMB + cb + 4 * cg] = make_float4(ox, oy, oz, ow);
    }
    __syncthreads();  // guards tb/wcs rewrite next chunk
  }
}

// ---------------------------------------------------------------------------
extern "C" void kernel_launch(void* const* d_in, const int* in_sizes, int n_in,
                              void* d_out, int out_size, void* d_ws, size_t ws_size,
                              hipStream_t stream) {
  (void)in_sizes; (void)n_in; (void)out_size; (void)ws_size;
  const int*   labels = (const int*)d_in[0];
  const float* in_adj = (const float*)d_in[1];
  const float* emb    = (const float*)d_in[2];
  const float* lw     = (const float*)d_in[3];
  float* out = (float*)d_out;

  float* adj = (float*)d_ws;                       // 2048*4096 f32 = 33.5 MB
  float* t0  = adj + (size_t)NB * L * L;           // 1601*300  f32 = 1.9 MB

  k_t0<<<NN, 320, 0, stream>>>(emb, lw, t0);
  k_adj<<<NB, 256, 0, stream>>>(labels, in_adj, adj);
  k_layer0<<<NB, 256, 0, stream>>>(labels, t0, adj, out);
  k_layerF<<<NB, 256, 0, stream>>>(lw + (size_t)EMB * EMB,     adj, out);
  k_layerF<<<NB, 256, 0, stream>>>(lw + 2 * (size_t)EMB * EMB, adj, out);
}

// Round 2
// 308.774 us; speedup vs baseline: 8.9720x; 8.9720x over previous
//
#include <hip/hip_runtime.h>

#define NN   1601
#define EMB  300
#define EMBV 75    // EMB/4
#define NB   2048
#define L    64

// ---------------------------------------------------------------------------
// C = A @ B   (M=K=N=300, row-major). One block per output row.
// ---------------------------------------------------------------------------
__global__ __launch_bounds__(320) void k_mm_nn(const float* __restrict__ A,
                                               const float* __restrict__ Bm,
                                               float* __restrict__ C) {
  __shared__ float arow[EMB];
  int i = blockIdx.x;
  for (int k = threadIdx.x; k < EMB; k += 320) arow[k] = A[(size_t)i * EMB + k];
  __syncthreads();
  int j = threadIdx.x;
  if (j < EMB) {
    float s = 0.f;
    #pragma unroll 4
    for (int k = 0; k < EMB; ++k) s += arow[k] * Bm[(size_t)k * EMB + j];
    C[(size_t)i * EMB + j] = s;
  }
}

// ---------------------------------------------------------------------------
// t0[n][e] = sum_k emb[n][k] * Wc[e][k]      (1601 x 300)
// ---------------------------------------------------------------------------
__global__ __launch_bounds__(320) void k_t0(const float* __restrict__ emb,
                                            const float* __restrict__ wc,
                                            float* __restrict__ t0) {
  __shared__ float4 row4[EMBV];
  int n = blockIdx.x;
  for (int k = threadIdx.x; k < EMB; k += 320)
    ((float*)row4)[k] = emb[(size_t)n * EMB + k];
  __syncthreads();
  int e = threadIdx.x;
  if (e < EMB) {
    const float4* w4 = (const float4*)wc + (size_t)e * EMBV;
    float ax = 0.f, ay = 0.f, az = 0.f, aw = 0.f;
    for (int k4 = 0; k4 < EMBV; ++k4) {
      float4 hv = row4[k4];
      float4 wv = w4[k4];
      ax += hv.x * wv.x; ay += hv.y * wv.y;
      az += hv.z * wv.z; aw += hv.w * wv.w;
    }
    t0[(size_t)n * EMB + e] = (ax + ay) + (az + aw);
  }
}

// ---------------------------------------------------------------------------
// Per batch: A = norm(in_adj[lab x lab] + I);  write A^3 to adj_out.
// 4x4 register tiles; LDS strides padded to 68 (16B-aligned float4 rows,
// max 2-way bank aliasing = free).
// ---------------------------------------------------------------------------
__global__ __launch_bounds__(256) void k_adj3(const int* __restrict__ labels,
                                              const float* __restrict__ in_adj,
                                              float* __restrict__ adj_out) {
  __shared__ int   lab[L];
  __shared__ float A[L][L + 4];
  __shared__ float B[L][L + 4];
  __shared__ float ps[4][L];
  __shared__ float dv[L];
  int b = blockIdx.x, tid = threadIdx.x;
  if (tid < L) lab[tid] = labels[(size_t)b * L + tid];
  __syncthreads();
  for (int idx = tid; idx < L * L; idx += 256) {
    int i = idx >> 6, j = idx & 63;
    float v = in_adj[(size_t)lab[i] * NN + lab[j]];
    if (i == j) v += 1.f;
    A[i][j] = v;
  }
  __syncthreads();
  {
    int j = tid & 63, q = tid >> 6;
    float s = 0.f;
    #pragma unroll
    for (int i = 0; i < 16; ++i) s += A[q * 16 + i][j];
    ps[q][j] = s;
  }
  __syncthreads();
  if (tid < L) {
    float s = ps[0][tid] + ps[1][tid] + ps[2][tid] + ps[3][tid];
    dv[tid] = 1.0f / sqrtf(s);
  }
  __syncthreads();
  for (int idx = tid; idx < L * L; idx += 256) {
    int i = idx >> 6, j = idx & 63;
    A[i][j] *= dv[i] * dv[j];
  }
  __syncthreads();

  int ti = tid >> 4, tj = tid & 15;
  int i0 = ti * 4, j0 = tj * 4;

  // B = A @ A
  {
    float acc[4][4] = {};
    #pragma unroll 4
    for (int k = 0; k < L; ++k) {
      float4 yv = *(const float4*)&A[k][j0];
      float x0 = A[i0 + 0][k], x1 = A[i0 + 1][k], x2 = A[i0 + 2][k], x3 = A[i0 + 3][k];
      acc[0][0] += x0 * yv.x; acc[0][1] += x0 * yv.y; acc[0][2] += x0 * yv.z; acc[0][3] += x0 * yv.w;
      acc[1][0] += x1 * yv.x; acc[1][1] += x1 * yv.y; acc[1][2] += x1 * yv.z; acc[1][3] += x1 * yv.w;
      acc[2][0] += x2 * yv.x; acc[2][1] += x2 * yv.y; acc[2][2] += x2 * yv.z; acc[2][3] += x2 * yv.w;
      acc[3][0] += x3 * yv.x; acc[3][1] += x3 * yv.y; acc[3][2] += x3 * yv.z; acc[3][3] += x3 * yv.w;
    }
    #pragma unroll
    for (int ii = 0; ii < 4; ++ii)
      *(float4*)&B[i0 + ii][j0] = make_float4(acc[ii][0], acc[ii][1], acc[ii][2], acc[ii][3]);
  }
  __syncthreads();

  // out = B @ A  (= A^3)
  {
    float acc[4][4] = {};
    #pragma unroll 4
    for (int k = 0; k < L; ++k) {
      float4 yv = *(const float4*)&A[k][j0];
      float x0 = B[i0 + 0][k], x1 = B[i0 + 1][k], x2 = B[i0 + 2][k], x3 = B[i0 + 3][k];
      acc[0][0] += x0 * yv.x; acc[0][1] += x0 * yv.y; acc[0][2] += x0 * yv.z; acc[0][3] += x0 * yv.w;
      acc[1][0] += x1 * yv.x; acc[1][1] += x1 * yv.y; acc[1][2] += x1 * yv.z; acc[1][3] += x1 * yv.w;
      acc[2][0] += x2 * yv.x; acc[2][1] += x2 * yv.y; acc[2][2] += x2 * yv.z; acc[2][3] += x2 * yv.w;
      acc[3][0] += x3 * yv.x; acc[3][1] += x3 * yv.y; acc[3][2] += x3 * yv.z; acc[3][3] += x3 * yv.w;
    }
    float* ob = adj_out + (size_t)b * (L * L);
    #pragma unroll
    for (int ii = 0; ii < 4; ++ii)
      *(float4*)&ob[(i0 + ii) * L + j0] = make_float4(acc[ii][0], acc[ii][1], acc[ii][2], acc[ii][3]);
  }
}

// ---------------------------------------------------------------------------
// out[b][i][e] = sum_j A3[b][i][j] * t0[lab[b][j]][e]
// t0 chunk-staged in LDS (4 KB) -> ~21 KB LDS total -> 7 blocks/CU.
// ---------------------------------------------------------------------------
__global__ __launch_bounds__(256) void k_layer0(const int* __restrict__ labels,
                                                const float* __restrict__ t0,
                                                const float* __restrict__ adj,
                                                float* __restrict__ hout) {
  __shared__ int   lab[L];
  __shared__ float am[L][L + 1];
  __shared__ float gb[L][16];
  int b = blockIdx.x, tid = threadIdx.x;
  if (tid < L) lab[tid] = labels[(size_t)b * L + tid];
  for (int idx = tid; idx < L * L; idx += 256)
    am[idx >> 6][idx & 63] = adj[(size_t)b * (L * L) + idx];
  __syncthreads();
  int i = tid & 63, cg = tid >> 6;
  float* ob = hout + ((size_t)b * L + i) * EMB;
  for (int cb = 0; cb < EMB; cb += 16) {
    int width = EMB - cb; if (width > 16) width = 16;   // 16, last = 12
    int g4 = width >> 2;                               // 4 or 3
    for (int idx = tid; idx < L * g4; idx += 256) {
      int row = idx / g4, q = idx - row * g4;
      *(float4*)&gb[row][4 * q] =
          *(const float4*)&t0[(size_t)lab[row] * EMB + cb + 4 * q];
    }
    __syncthreads();
    if (4 * cg < width) {
      float ox = 0.f, oy = 0.f, oz = 0.f, ow = 0.f;
      #pragma unroll 8
      for (int j = 0; j < L; ++j) {
        float  a  = am[i][j];
        float4 tv = *(const float4*)&gb[j][4 * cg];
        ox += a * tv.x; oy += a * tv.y; oz += a * tv.z; ow += a * tv.w;
      }
      *(float4*)&ob[cb + 4 * cg] = make_float4(ox, oy, oz, ow);
    }
    __syncthreads();
  }
}

// ---------------------------------------------------------------------------
extern "C" void kernel_launch(void* const* d_in, const int* in_sizes, int n_in,
                              void* d_out, int out_size, void* d_ws, size_t ws_size,
                              hipStream_t stream) {
  (void)in_sizes; (void)n_in; (void)out_size; (void)ws_size;
  const int*   labels = (const int*)d_in[0];
  const float* in_adj = (const float*)d_in[1];
  const float* emb    = (const float*)d_in[2];
  const float* lw     = (const float*)d_in[3];
  float* out = (float*)d_out;

  float* adj3 = (float*)d_ws;                     // 2048*4096 f32 = 33.55 MB
  float* t0   = adj3 + (size_t)NB * L * L;        // 1601*300 f32  = 1.92 MB
  // T and Wc transiently alias the adj3 buffer (dead before k_adj3 writes it)
  float* T    = adj3;                             // 300*300
  float* Wc   = adj3 + 90000;                     // 300*300

  const float* W1 = lw;
  const float* W2 = lw + (size_t)EMB * EMB;
  const float* W3 = lw + 2 * (size_t)EMB * EMB;

  k_mm_nn<<<EMB, 320, 0, stream>>>(W3, W2, T);    // T  = W3@W2
  k_mm_nn<<<EMB, 320, 0, stream>>>(T, W1, Wc);    // Wc = W3@W2@W1
  k_t0  <<<NN, 320, 0, stream>>>(emb, Wc, t0);    // t0 = emb@Wc^T
  k_adj3<<<NB, 256, 0, stream>>>(labels, in_adj, adj3);
  k_layer0<<<NB, 256, 0, stream>>>(labels, t0, adj3, out);
}

// Round 3
// 243.284 us; speedup vs baseline: 11.3872x; 1.2692x over previous
//
#include <hip/hip_runtime.h>

#define NN   1601
#define EMB  300
#define NB   2048
#define L    64
#define TSTR 304   // t0bf row stride in bf16 elements

typedef __attribute__((ext_vector_type(8))) short bf16x8;
typedef __attribute__((ext_vector_type(4))) float f32x4;

static __device__ __forceinline__ ushort f2b(float x) {
  union { float f; unsigned u; } c; c.f = x;
  unsigned u = c.u;
  unsigned r = (u + 0x7FFFu + ((u >> 16) & 1u)) >> 16;   // RNE
  return (ushort)r;
}

// ---------------------------------------------------------------------------
// C = A @ B   (300x300x300 f32, row-major). One block per output row.
// ---------------------------------------------------------------------------
__global__ __launch_bounds__(320) void k_mm_nn(const float* __restrict__ A,
                                               const float* __restrict__ Bm,
                                               float* __restrict__ C) {
  __shared__ float arow[EMB];
  int i = blockIdx.x;
  for (int k = threadIdx.x; k < EMB; k += 320) arow[k] = A[(size_t)i * EMB + k];
  __syncthreads();
  int j = threadIdx.x;
  if (j < EMB) {
    float s = 0.f;
    #pragma unroll 4
    for (int k = 0; k < EMB; ++k) s += arow[k] * Bm[(size_t)k * EMB + j];
    C[(size_t)i * EMB + j] = s;
  }
}

// ---------------------------------------------------------------------------
// t0bf[n][e] = bf16( sum_k emb[n][k] * Wc[e][k] )   (1601 x 300, stride 304)
// ---------------------------------------------------------------------------
__global__ __launch_bounds__(320) void k_t0bf(const float* __restrict__ emb,
                                              const float* __restrict__ wc,
                                              ushort* __restrict__ t0bf) {
  __shared__ float4 row4[75];
  int n = blockIdx.x;
  for (int k = threadIdx.x; k < EMB; k += 320)
    ((float*)row4)[k] = emb[(size_t)n * EMB + k];
  __syncthreads();
  int e = threadIdx.x;
  if (e < EMB) {
    const float4* w4 = (const float4*)wc + (size_t)e * 75;
    float ax = 0.f, ay = 0.f, az = 0.f, aw = 0.f;
    for (int k4 = 0; k4 < 75; ++k4) {
      float4 hv = row4[k4];
      float4 wv = w4[k4];
      ax += hv.x * wv.x; ay += hv.y * wv.y;
      az += hv.z * wv.z; aw += hv.w * wv.w;
    }
    t0bf[(size_t)n * TSTR + e] = f2b((ax + ay) + (az + aw));
  }
}

// ---------------------------------------------------------------------------
// Fused per-batch kernel:
//   A = norm(in_adj[lab x lab] + I)          (f32, LDS)
//   A3 = A*A*A                               (f32 4x4 reg tiles, cast -> bf16)
//   out[b] = A3 @ t0[lab]                    (bf16 MFMA 16x16x32, f32 out)
// ---------------------------------------------------------------------------
__global__ __launch_bounds__(256) void k_fused(const int* __restrict__ labels,
                                               const float* __restrict__ in_adj,
                                               const ushort* __restrict__ t0bf,
                                               float* __restrict__ out) {
  __shared__ int    lab[L];
  __shared__ float  dv[L];
  __shared__ float  ps[4][L];
  __shared__ float  Af[L][68];      // A (then scaled A)
  __shared__ float  Bf[L][68];      // A^2
  __shared__ ushort A3b[L][72];     // A^3 bf16, stride 144 B (bank shift 4/row)
  __shared__ ushort Tt[80][72];     // T0g^T chunk: Tt[e_local][j]

  int b = blockIdx.x, tid = threadIdx.x;
  if (tid < L) lab[tid] = labels[(size_t)b * L + tid];
  __syncthreads();

  // gather neighbor + I
  for (int idx = tid; idx < L * L; idx += 256) {
    int i = idx >> 6, j = idx & 63;
    float v = in_adj[(size_t)lab[i] * NN + lab[j]];
    if (i == j) v += 1.f;
    Af[i][j] = v;
  }
  __syncthreads();
  // column sums -> dv
  {
    int j = tid & 63, q = tid >> 6;
    float s = 0.f;
    #pragma unroll
    for (int i = 0; i < 16; ++i) s += Af[q * 16 + i][j];
    ps[q][j] = s;
  }
  __syncthreads();
  if (tid < L) {
    float s = ps[0][tid] + ps[1][tid] + ps[2][tid] + ps[3][tid];
    dv[tid] = 1.0f / sqrtf(s);
  }
  __syncthreads();
  for (int idx = tid; idx < L * L; idx += 256) {
    int i = idx >> 6, j = idx & 63;
    Af[i][j] *= dv[i] * dv[j];
  }
  __syncthreads();

  int ti = tid >> 4, tj = tid & 15;
  int i0 = ti * 4, j0 = tj * 4;

  // Bf = A @ A
  {
    float acc[4][4] = {};
    #pragma unroll 4
    for (int k = 0; k < L; ++k) {
      float4 yv = *(const float4*)&Af[k][j0];
      float x0 = Af[i0 + 0][k], x1 = Af[i0 + 1][k], x2 = Af[i0 + 2][k], x3 = Af[i0 + 3][k];
      acc[0][0] += x0 * yv.x; acc[0][1] += x0 * yv.y; acc[0][2] += x0 * yv.z; acc[0][3] += x0 * yv.w;
      acc[1][0] += x1 * yv.x; acc[1][1] += x1 * yv.y; acc[1][2] += x1 * yv.z; acc[1][3] += x1 * yv.w;
      acc[2][0] += x2 * yv.x; acc[2][1] += x2 * yv.y; acc[2][2] += x2 * yv.z; acc[2][3] += x2 * yv.w;
      acc[3][0] += x3 * yv.x; acc[3][1] += x3 * yv.y; acc[3][2] += x3 * yv.z; acc[3][3] += x3 * yv.w;
    }
    #pragma unroll
    for (int ii = 0; ii < 4; ++ii)
      *(float4*)&Bf[i0 + ii][j0] = make_float4(acc[ii][0], acc[ii][1], acc[ii][2], acc[ii][3]);
  }
  __syncthreads();

  // A3 = Bf @ A  -> bf16 A3b
  {
    float acc[4][4] = {};
    #pragma unroll 4
    for (int k = 0; k < L; ++k) {
      float4 yv = *(const float4*)&Af[k][j0];
      float x0 = Bf[i0 + 0][k], x1 = Bf[i0 + 1][k], x2 = Bf[i0 + 2][k], x3 = Bf[i0 + 3][k];
      acc[0][0] += x0 * yv.x; acc[0][1] += x0 * yv.y; acc[0][2] += x0 * yv.z; acc[0][3] += x0 * yv.w;
      acc[1][0] += x1 * yv.x; acc[1][1] += x1 * yv.y; acc[1][2] += x1 * yv.z; acc[1][3] += x1 * yv.w;
      acc[2][0] += x2 * yv.x; acc[2][1] += x2 * yv.y; acc[2][2] += x2 * yv.z; acc[2][3] += x2 * yv.w;
      acc[3][0] += x3 * yv.x; acc[3][1] += x3 * yv.y; acc[3][2] += x3 * yv.z; acc[3][3] += x3 * yv.w;
    }
    #pragma unroll
    for (int ii = 0; ii < 4; ++ii) {
      ushort4 pk;
      pk.x = f2b(acc[ii][0]); pk.y = f2b(acc[ii][1]);
      pk.z = f2b(acc[ii][2]); pk.w = f2b(acc[ii][3]);
      *(ushort4*)&A3b[i0 + ii][j0] = pk;
    }
  }
  __syncthreads();

  // ---- MFMA phase: out[b] = A3 @ T0g, chunked over e -------------------
  int lane = tid & 63, w = tid >> 6;
  int m0 = 16 * w;
  int lrow = lane & 15, lk = lane >> 4;

  // A-fragments for this wave's row strip (reused across all col tiles)
  bf16x8 a0 = *(const bf16x8*)&A3b[m0 + lrow][8 * lk];
  bf16x8 a1 = *(const bf16x8*)&A3b[m0 + lrow][32 + 8 * lk];

  int jme = lane;                 // staging: this lane's graph-node column
  int g   = tid >> 6;             // staging: e-offset group
  const ushort* trow = t0bf + (size_t)lab[jme] * TSTR;

  for (int c = 0; c < 4; ++c) {
    int base = 80 * c;
    int ext  = (c == 3) ? 64 : 80;
    // stage Tt[e][j] = t0bf[lab[j]][base+e]  (bf16x8 loads, u16 LDS writes)
    for (int e = 8 * g; e < ext; e += 32) {
      int4 raw = *(const int4*)(trow + base + e);
      const ushort* tv = (const ushort*)&raw;
      #pragma unroll
      for (int q = 0; q < 8; ++q) Tt[e + q][jme] = tv[q];
    }
    __syncthreads();

    int ntile = ext >> 4;
    for (int t = 0; t < ntile; ++t) {
      f32x4 acc = {0.f, 0.f, 0.f, 0.f};
      bf16x8 b0 = *(const bf16x8*)&Tt[16 * t + lrow][8 * lk];
      bf16x8 b1 = *(const bf16x8*)&Tt[16 * t + lrow][32 + 8 * lk];
      acc = __builtin_amdgcn_mfma_f32_16x16x32_bf16(a0, b0, acc, 0, 0, 0);
      acc = __builtin_amdgcn_mfma_f32_16x16x32_bf16(a1, b1, acc, 0, 0, 0);
      int ecol = base + 16 * t + lrow;
      if (ecol < EMB) {
        float* ob = out + ((size_t)b * L + m0 + 4 * lk) * EMB + ecol;
        ob[0 * EMB] = acc[0];
        ob[1 * EMB] = acc[1];
        ob[2 * EMB] = acc[2];
        ob[3 * EMB] = acc[3];
      }
    }
    __syncthreads();
  }
}

// ---------------------------------------------------------------------------
extern "C" void kernel_launch(void* const* d_in, const int* in_sizes, int n_in,
                              void* d_out, int out_size, void* d_ws, size_t ws_size,
                              hipStream_t stream) {
  (void)in_sizes; (void)n_in; (void)out_size; (void)ws_size;
  const int*   labels = (const int*)d_in[0];
  const float* in_adj = (const float*)d_in[1];
  const float* emb    = (const float*)d_in[2];
  const float* lw     = (const float*)d_in[3];
  float* out = (float*)d_out;

  float*  T    = (float*)d_ws;             // 300*300 f32
  float*  Wc   = T + 90000;                // 300*300 f32
  ushort* t0bf = (ushort*)(Wc + 90000);    // 1601*304 bf16

  const float* W1 = lw;
  const float* W2 = lw + (size_t)EMB * EMB;
  const float* W3 = lw + 2 * (size_t)EMB * EMB;

  k_mm_nn<<<EMB, 320, 0, stream>>>(W3, W2, T);     // T  = W3@W2
  k_mm_nn<<<EMB, 320, 0, stream>>>(T, W1, Wc);     // Wc = W3@W2@W1
  k_t0bf <<<NN, 320, 0, stream>>>(emb, Wc, t0bf);  // t0 = bf16(emb@Wc^T)
  k_fused<<<NB, 256, 0, stream>>>(labels, in_adj, t0bf, out);
}

// Round 4
// 171.054 us; speedup vs baseline: 16.1956x; 1.4223x over previous
//
#include <hip/hip_runtime.h>

#define NN   1601
#define EMB  300
#define NB   2048
#define L    64
#define TSTR 304   // t0bf row stride (u16)
#define S    72    // LDS matrix stride (u16) -> 144B rows, 16B-aligned frags

typedef __attribute__((ext_vector_type(8))) short bf16x8;
typedef __attribute__((ext_vector_type(4))) float f32x4;

static __device__ __forceinline__ ushort f2b(float x) {
  union { float f; unsigned u; } c; c.f = x;
  unsigned u = c.u;
  return (ushort)((u + 0x7FFFu + ((u >> 16) & 1u)) >> 16);   // RNE
}
static __device__ __forceinline__ float b2f(ushort h) {
  union { unsigned u; float f; } c; c.u = ((unsigned)h) << 16; return c.f;
}

#define LD8(p, r, c) (*(const bf16x8*)&(p)[(size_t)(r) * S + (c)])
#define MFMA(a, bm, acc) __builtin_amdgcn_mfma_f32_16x16x32_bf16((a), (bm), (acc), 0, 0, 0)

// ---------------------------------------------------------------------------
// C = A @ B   (300x300x300 f32). 4 independent accumulator chains for ILP.
// ---------------------------------------------------------------------------
__global__ __launch_bounds__(320) void k_mm_nn(const float* __restrict__ A,
                                               const float* __restrict__ Bm,
                                               float* __restrict__ C) {
  __shared__ float arow[EMB];
  int i = blockIdx.x;
  for (int k = threadIdx.x; k < EMB; k += 320) arow[k] = A[(size_t)i * EMB + k];
  __syncthreads();
  int j = threadIdx.x;
  if (j < EMB) {
    float s0 = 0.f, s1 = 0.f, s2 = 0.f, s3 = 0.f;
    #pragma unroll 2
    for (int k = 0; k < EMB; k += 4) {
      s0 += arow[k + 0] * Bm[(size_t)(k + 0) * EMB + j];
      s1 += arow[k + 1] * Bm[(size_t)(k + 1) * EMB + j];
      s2 += arow[k + 2] * Bm[(size_t)(k + 2) * EMB + j];
      s3 += arow[k + 3] * Bm[(size_t)(k + 3) * EMB + j];
    }
    C[(size_t)i * EMB + j] = (s0 + s1) + (s2 + s3);
  }
}

// ---------------------------------------------------------------------------
// t0bf[n][e] = bf16( sum_k emb[n][k] * Wc[e][k] ), 8 rows per block
// (reuses each lane's wc-row stream across 8 emb rows; pads cols 300..303=0)
// ---------------------------------------------------------------------------
__global__ __launch_bounds__(320) void k_t0bf(const float* __restrict__ emb,
                                              const float* __restrict__ wc,
                                              ushort* __restrict__ t0bf) {
  __shared__ float4 rows[8][75];
  int n0 = blockIdx.x * 8, tid = threadIdx.x;
  for (int idx = tid; idx < 8 * EMB; idx += 320) {
    int r = idx / EMB, k = idx - r * EMB;
    int n = n0 + r;
    ((float*)&rows[r][0])[k] = (n < NN) ? emb[(size_t)n * EMB + k] : 0.f;
  }
  __syncthreads();
  int e = tid;
  if (e < EMB) {
    const float4* w4 = (const float4*)wc + (size_t)e * 75;
    float acc[8] = {};
    for (int k4 = 0; k4 < 75; ++k4) {
      float4 wv = w4[k4];
      #pragma unroll
      for (int r = 0; r < 8; ++r) {
        float4 hv = rows[r][k4];
        acc[r] += hv.x * wv.x + hv.y * wv.y + hv.z * wv.z + hv.w * wv.w;
      }
    }
    #pragma unroll
    for (int r = 0; r < 8; ++r) {
      int n = n0 + r;
      if (n < NN) t0bf[(size_t)n * TSTR + e] = f2b(acc[r]);
    }
  } else if (e < TSTR) {  // zero the pad columns
    #pragma unroll
    for (int r = 0; r < 8; ++r) {
      int n = n0 + r;
      if (n < NN) t0bf[(size_t)n * TSTR + e] = 0;
    }
  }
}

// ---------------------------------------------------------------------------
// Fused per-batch kernel, all-MFMA:
//   A = norm(gather+I)              (raw in VGPRs, colsum folded into gather)
//   A2 = A*A   via hi/lo bf16 split (3-term, ~f32 accuracy), stored as A2^T
//   A3 = A*A2  via hi/lo split      -> bf16 row-major
//   out[b] = A3 @ t0[lab]           (Tt chunks overlay the dead Ahi/Alo LDS)
// ---------------------------------------------------------------------------
__global__ __launch_bounds__(256, 4) void k_fused(const int* __restrict__ labels,
                                                  const float* __restrict__ in_adj,
                                                  const ushort* __restrict__ t0bf,
                                                  float* __restrict__ out) {
  __shared__ __align__(16) ushort arena[4 * L * S];   // 36.9 KB
  ushort* Ahi = arena;              // later: Tt chunk (with Alo region)
  ushort* Alo = arena + L * S;
  ushort* AT2 = arena + 2 * L * S;  // AhiT -> A2hiT -> A3b
  ushort* AT3 = arena + 3 * L * S;  // AloT -> A2loT
  __shared__ int   lab[L];
  __shared__ float ps[4][L];
  __shared__ float dv[L];

  int b = blockIdx.x, tid = threadIdx.x;
  int j = tid & 63, g = tid >> 6;
  if (tid < L) lab[tid] = labels[(size_t)b * L + tid];
  __syncthreads();
  int labj = lab[j];

  // gather (raw in regs) + fused column sums
  float raw[16];
  float cs = 0.f;
  #pragma unroll
  for (int q = 0; q < 16; ++q) {
    int i = g + 4 * q;
    float v = in_adj[(size_t)lab[i] * NN + labj];
    v += (i == j) ? 1.f : 0.f;
    raw[q] = v; cs += v;
  }
  ps[g][j] = cs;
  __syncthreads();
  if (tid < L) dv[tid] = 1.f / sqrtf(ps[0][tid] + ps[1][tid] + ps[2][tid] + ps[3][tid]);
  __syncthreads();

  // scale + hi/lo split + direct/transposed stores
  float dj = dv[j];
  #pragma unroll
  for (int q = 0; q < 16; ++q) {
    int i = g + 4 * q;
    float a = raw[q] * dv[i] * dj;
    ushort hi = f2b(a);
    ushort lo = f2b(a - b2f(hi));
    Ahi[(size_t)i * S + j] = hi;
    Alo[(size_t)i * S + j] = lo;
    AT2[(size_t)j * S + i] = hi;
    AT3[(size_t)j * S + i] = lo;
  }
  __syncthreads();

  int lane = tid & 63, w = tid >> 6;
  int lrow = lane & 15, lk = lane >> 4;
  int m0 = 16 * w;

  // A-side fragments of A (rows), reused for A^2 and A^3
  bf16x8 ah0 = LD8(Ahi, m0 + lrow, 8 * lk);
  bf16x8 ah1 = LD8(Ahi, m0 + lrow, 32 + 8 * lk);
  bf16x8 al0 = LD8(Alo, m0 + lrow, 8 * lk);
  bf16x8 al1 = LD8(Alo, m0 + lrow, 32 + 8 * lk);

  // ---- A2 = A @ A  (3-term hi/lo) -> write A2^T into AT2/AT3 ----
  {
    f32x4 acc[4];
    #pragma unroll
    for (int t = 0; t < 4; ++t) {
      f32x4 a = {0.f, 0.f, 0.f, 0.f};
      bf16x8 bh = LD8(AT2, 16 * t + lrow, 8 * lk);
      bf16x8 bl = LD8(AT3, 16 * t + lrow, 8 * lk);
      a = MFMA(ah0, bh, a); a = MFMA(ah0, bl, a); a = MFMA(al0, bh, a);
      bh = LD8(AT2, 16 * t + lrow, 32 + 8 * lk);
      bl = LD8(AT3, 16 * t + lrow, 32 + 8 * lk);
      a = MFMA(ah1, bh, a); a = MFMA(ah1, bl, a); a = MFMA(al1, bh, a);
      acc[t] = a;
    }
    __syncthreads();   // all reads of AT2/AT3 done
    #pragma unroll
    for (int t = 0; t < 4; ++t) {
      ushort4 h4, l4;
      float x;
      x = acc[t][0]; h4.x = f2b(x); l4.x = f2b(x - b2f(h4.x));
      x = acc[t][1]; h4.y = f2b(x); l4.y = f2b(x - b2f(h4.y));
      x = acc[t][2]; h4.z = f2b(x); l4.z = f2b(x - b2f(h4.z));
      x = acc[t][3]; h4.w = f2b(x); l4.w = f2b(x - b2f(h4.w));
      // acc[t][r] = A2[m0+4lk+r][16t+lrow]  ->  A2T[16t+lrow][m0+4lk+r]
      *(ushort4*)&AT2[(size_t)(16 * t + lrow) * S + m0 + 4 * lk] = h4;
      *(ushort4*)&AT3[(size_t)(16 * t + lrow) * S + m0 + 4 * lk] = l4;
    }
  }
  __syncthreads();

  // ---- A3 = A @ A2  (3-term) -> bf16 row-major into AT2 ----
  {
    f32x4 acc[4];
    #pragma unroll
    for (int t = 0; t < 4; ++t) {
      f32x4 a = {0.f, 0.f, 0.f, 0.f};
      bf16x8 bh = LD8(AT2, 16 * t + lrow, 8 * lk);
      bf16x8 bl = LD8(AT3, 16 * t + lrow, 8 * lk);
      a = MFMA(ah0, bh, a); a = MFMA(ah0, bl, a); a = MFMA(al0, bh, a);
      bh = LD8(AT2, 16 * t + lrow, 32 + 8 * lk);
      bl = LD8(AT3, 16 * t + lrow, 32 + 8 * lk);
      a = MFMA(ah1, bh, a); a = MFMA(ah1, bl, a); a = MFMA(al1, bh, a);
      acc[t] = a;
    }
    __syncthreads();   // all reads of AT2/AT3 done
    #pragma unroll
    for (int t = 0; t < 4; ++t)
      #pragma unroll
      for (int r = 0; r < 4; ++r)
        AT2[(size_t)(m0 + 4 * lk + r) * S + 16 * t + lrow] = f2b(acc[t][r]);
  }
  __syncthreads();

  // ---- out = A3 @ T0g, Tt chunks overlay Ahi/Alo region ----
  bf16x8 fa0 = LD8(AT2, m0 + lrow, 8 * lk);
  bf16x8 fa1 = LD8(AT2, m0 + lrow, 32 + 8 * lk);
  ushort* Tt = arena;                      // [80][S] max = 5760 u16 < 2*L*S
  const ushort* trow = t0bf + (size_t)labj * TSTR;

  for (int c = 0; c < 4; ++c) {
    int rows80 = (c == 3) ? 64 : 80;
    for (int e = 8 * g; e < rows80; e += 32) {
      union { int4 v; ushort u[8]; } uu;
      uu.v = *(const int4*)(trow + 80 * c + e);
      #pragma unroll
      for (int q = 0; q < 8; ++q) Tt[(size_t)(e + q) * S + j] = uu.u[q];
    }
    __syncthreads();
    int nt = (c == 3) ? 4 : 5;
    for (int t = 0; t < nt; ++t) {
      bf16x8 b0 = LD8(Tt, 16 * t + lrow, 8 * lk);
      bf16x8 b1 = LD8(Tt, 16 * t + lrow, 32 + 8 * lk);
      f32x4 o = {0.f, 0.f, 0.f, 0.f};
      o = MFMA(fa0, b0, o);
      o = MFMA(fa1, b1, o);
      int ecol = 80 * c + 16 * t + lrow;
      if (ecol < EMB) {
        float* ob = out + ((size_t)b * L + m0 + 4 * lk) * EMB + ecol;
        ob[0]       = o[0];
        ob[EMB]     = o[1];
        ob[2 * EMB] = o[2];
        ob[3 * EMB] = o[3];
      }
    }
    __syncthreads();
  }
}

// ---------------------------------------------------------------------------
extern "C" void kernel_launch(void* const* d_in, const int* in_sizes, int n_in,
                              void* d_out, int out_size, void* d_ws, size_t ws_size,
                              hipStream_t stream) {
  (void)in_sizes; (void)n_in; (void)out_size; (void)ws_size;
  const int*   labels = (const int*)d_in[0];
  const float* in_adj = (const float*)d_in[1];
  const float* emb    = (const float*)d_in[2];
  const float* lw     = (const float*)d_in[3];
  float* out = (float*)d_out;

  float*  T    = (float*)d_ws;             // 300*300 f32
  float*  Wc   = T + 90000;                // 300*300 f32
  ushort* t0bf = (ushort*)(Wc + 90000);    // 1601*304 bf16

  const float* W1 = lw;
  const float* W2 = lw + (size_t)EMB * EMB;
  const float* W3 = lw + 2 * (size_t)EMB * EMB;

  k_mm_nn<<<EMB, 320, 0, stream>>>(W3, W2, T);        // T  = W3@W2
  k_mm_nn<<<EMB, 320, 0, stream>>>(T, W1, Wc);        // Wc = W3@W2@W1
  k_t0bf <<<(NN + 7) / 8, 320, 0, stream>>>(emb, Wc, t0bf);
  k_fused<<<NB, 256, 0, stream>>>(labels, in_adj, t0bf, out);
}